// Round 1
// baseline (491.191 us; speedup 1.0000x reference)
//
#include <hip/hip_runtime.h>
#include <hip/hip_bf16.h>

// TinyLocalWindowAttention on MI355X (gfx950)
// x:(32,256,112,112) f32, 7x7 windows (112%7==0 -> no padding), 8192 windows.
// One block (256 thr = 4 waves) per window; bf16 MFMA 16x16x32 throughout.

typedef short bf16x8 __attribute__((ext_vector_type(8)));   // 8 bf16 (4 VGPRs)
typedef float f32x4 __attribute__((ext_vector_type(4)));

static __device__ __forceinline__ unsigned short f2bf(float f) {
    unsigned int u = __float_as_uint(f);
    u += 0x7fffu + ((u >> 16) & 1u);          // RNE
    return (unsigned short)(u >> 16);
}
static __device__ __forceinline__ float bf2f(unsigned int hs) {
    return __uint_as_float(hs << 16);
}

#define PROJ_OFF 65536   // bf16 elems offset of proj frags in ws

// ---- pre-pass: Wqkv[256][256], Wproj[128][256] f32 -> bf16 B-fragment arrays ----
// qkv frag: dst[((ntile*8+kt)*64+lane)*8+j] = W[(kt*32+(lane>>4)*8+j)][ntile*16+(lane&15)]
__global__ void prep_weights(const float* __restrict__ Wqkv,
                             const float* __restrict__ Wproj,
                             unsigned short* __restrict__ ws) {
    int tid = blockIdx.x * 256 + threadIdx.x;
    if (tid < 8192) {                         // 16 ntiles * 8 ktiles * 64 lanes
        int lane = tid & 63, f = tid >> 6;
        int kt = f & 7, nt = f >> 3;
        int kbase = kt * 32 + (lane >> 4) * 8;
        int col = nt * 16 + (lane & 15);
        unsigned short t[8];
        #pragma unroll
        for (int j = 0; j < 8; ++j) t[j] = f2bf(Wqkv[(kbase + j) * 256 + col]);
        uint4 u;
        u.x = (unsigned)t[0] | ((unsigned)t[1] << 16);
        u.y = (unsigned)t[2] | ((unsigned)t[3] << 16);
        u.z = (unsigned)t[4] | ((unsigned)t[5] << 16);
        u.w = (unsigned)t[6] | ((unsigned)t[7] << 16);
        *reinterpret_cast<uint4*>(&ws[tid * 8]) = u;
    } else if (tid < 12288) {                 // 16 ntiles * 4 ktiles * 64 lanes
        int i2 = tid - 8192;
        int lane = i2 & 63, f = i2 >> 6;
        int kt = f & 3, nt = f >> 2;
        int kbase = kt * 32 + (lane >> 4) * 8;
        int col = nt * 16 + (lane & 15);
        unsigned short t[8];
        #pragma unroll
        for (int j = 0; j < 8; ++j) t[j] = f2bf(Wproj[(kbase + j) * 256 + col]);
        uint4 u;
        u.x = (unsigned)t[0] | ((unsigned)t[1] << 16);
        u.y = (unsigned)t[2] | ((unsigned)t[3] << 16);
        u.z = (unsigned)t[4] | ((unsigned)t[5] << 16);
        u.w = (unsigned)t[6] | ((unsigned)t[7] << 16);
        *reinterpret_cast<uint4*>(&ws[PROJ_OFF + i2 * 8]) = u;
    }
}

// LDS regions (64 KB total -> 2 blocks/CU):
//  r1 32KB: xa[64][256] (bf16, XOR-swz) -> p_s[4][64][64] -> out_s[64][256]
//  r2 16KB: qkv_s[64][128] (q cols 0..63, k cols 64..127)
//  r3 16KB: vT[4 heads][32 dims][64 toks] -> o_s[64][128]
// swizzle: elem(row,col,W) = row*W + (((col>>3) ^ (row&7))<<3) + (col&7)

__global__ __launch_bounds__(256, 2) void win_attn(
    const float* __restrict__ x,
    const unsigned short* __restrict__ wf,
    const float* __restrict__ bqkv,
    const float* __restrict__ bproj,
    float* __restrict__ out)
{
    __shared__ __align__(16) unsigned short r1[16384];
    __shared__ __align__(16) unsigned short r2[8192];
    __shared__ __align__(16) unsigned short r3[8192];

    const int tid  = threadIdx.x;
    const int lane = tid & 63;
    const int wave = tid >> 6;
    const int lr   = lane & 15;       // row/col within 16-tile
    const int kg   = lane >> 4;       // k-group (0..3)

    // XCD swizzle: 8192 % 8 == 0, contiguous 1024 windows per XCD
    const int bid = (int)blockIdx.x;
    const int L   = (bid & 7) * 1024 + (bid >> 3);
    const int b   = L >> 8;
    const int rem = L & 255;
    const int h0 = (rem >> 4) * 7;
    const int w0 = (rem & 15) * 7;
    const int xwin = (b * 256) * 12544 + h0 * 112 + w0;

    // ---- phase A: zero pad rows 49..63, load x window -> xa (bf16) ----
    for (int i = tid; i < 15 * 128; i += 256)
        reinterpret_cast<unsigned int*>(r1)[49 * 128 + i] = 0u;

    if (lane < 49) {
        const int lb = xwin + (lane / 7) * 112 + (lane % 7);
        #pragma unroll 8
        for (int it = 0; it < 32; ++it) {
            const int c0 = wave * 64 + it * 2;
            const float v0 = x[lb + c0 * 12544];
            const float v1 = x[lb + (c0 + 1) * 12544];
            const unsigned int pk = (unsigned int)f2bf(v0) | ((unsigned int)f2bf(v1) << 16);
            const int e = lane * 256 + (((c0 >> 3) ^ (lane & 7)) << 3) + (c0 & 7);
            *reinterpret_cast<unsigned int*>(&r1[e]) = pk;
        }
    }
    __syncthreads();

    // ---- phase B: qkv = xa @ Wqkv ; wave w owns output cols [64w, 64w+64) ----
    f32x4 acc[4][4];
    #pragma unroll
    for (int m = 0; m < 4; ++m)
        #pragma unroll
        for (int nn = 0; nn < 4; ++nn)
            acc[m][nn] = f32x4{0.f, 0.f, 0.f, 0.f};

    #pragma unroll
    for (int kt = 0; kt < 8; ++kt) {
        bf16x8 a[4], bw[4];
        #pragma unroll
        for (int m = 0; m < 4; ++m) {
            const int row = lr + 16 * m;
            const int ch  = (kt * 4 + kg) ^ (row & 7);
            a[m] = *reinterpret_cast<const bf16x8*>(&r1[row * 256 + ch * 8]);
        }
        #pragma unroll
        for (int nn = 0; nn < 4; ++nn) {
            const int nt = wave * 4 + nn;
            bw[nn] = *reinterpret_cast<const bf16x8*>(&wf[((nt * 8 + kt) * 64 + lane) * 8]);
        }
        #pragma unroll
        for (int m = 0; m < 4; ++m)
            #pragma unroll
            for (int nn = 0; nn < 4; ++nn)
                acc[m][nn] = __builtin_amdgcn_mfma_f32_16x16x32_bf16(a[m], bw[nn], acc[m][nn], 0, 0, 0);
    }

    // epilogue: +bias; waves 0,1 -> qkv_s (q,k); waves 2,3 -> vT
    #pragma unroll
    for (int nn = 0; nn < 4; ++nn) {
        const int colg = wave * 64 + nn * 16 + lr;
        const float bq = bqkv[colg];
        #pragma unroll
        for (int m = 0; m < 4; ++m)
            #pragma unroll
            for (int r = 0; r < 4; ++r) {
                const int row = kg * 4 + r + 16 * m;        // token
                const unsigned short hv = f2bf(acc[m][nn][r] + bq);
                if (wave < 2) {
                    r2[row * 128 + (((colg >> 3) ^ (row & 7)) << 3) + (colg & 7)] = hv;
                } else {
                    const int vc = colg - 128;
                    const int hh = vc >> 5, d = vc & 31;
                    r3[hh * 2048 + d * 64 + (((row >> 3) ^ (d & 7)) << 3) + (row & 7)] = hv;
                }
            }
    }
    __syncthreads();

    // ---- phase C: attention, head h = wave; S = q_h @ k_h^T (K=16 padded to 32) ----
    const int h = wave;
    f32x4 s[4][4];
    {
        bf16x8 qf[4], kf[4];
        const bf16x8 zf = {0, 0, 0, 0, 0, 0, 0, 0};
        #pragma unroll
        for (int m = 0; m < 4; ++m) {
            if (lane < 32) {
                const int row = lr + 16 * m;
                const int col = h * 16 + kg * 8;
                qf[m] = *reinterpret_cast<const bf16x8*>(&r2[row * 128 + (((col >> 3) ^ (row & 7)) << 3)]);
            } else qf[m] = zf;
        }
        #pragma unroll
        for (int nt = 0; nt < 4; ++nt) {
            if (lane < 32) {
                const int row = lr + 16 * nt;               // k-token = B col
                const int col = 64 + h * 16 + kg * 8;
                kf[nt] = *reinterpret_cast<const bf16x8*>(&r2[row * 128 + (((col >> 3) ^ (row & 7)) << 3)]);
            } else kf[nt] = zf;
        }
        #pragma unroll
        for (int m = 0; m < 4; ++m)
            #pragma unroll
            for (int nt = 0; nt < 4; ++nt) {
                f32x4 z = f32x4{0.f, 0.f, 0.f, 0.f};
                s[m][nt] = __builtin_amdgcn_mfma_f32_16x16x32_bf16(qf[m], kf[nt], z, 0, 0, 0);
            }
    }

    // softmax over k-token cols (valid cols 0..48), write normalized P bf16 -> p_s (r1)
    {
        const bool v3 = (lr == 0);  // in nt==3 only col 48 is valid
        #pragma unroll
        for (int m = 0; m < 4; ++m) {
            float mx[4], sum[4];
            #pragma unroll
            for (int r = 0; r < 4; ++r) {
                const float a0 = fmaxf(s[m][0][r], s[m][1][r]);
                const float a1 = v3 ? fmaxf(s[m][2][r], s[m][3][r]) : s[m][2][r];
                mx[r] = fmaxf(a0, a1);
            }
            #pragma unroll
            for (int d = 1; d <= 8; d <<= 1)
                #pragma unroll
                for (int r = 0; r < 4; ++r)
                    mx[r] = fmaxf(mx[r], __shfl_xor(mx[r], d, 64));
            #pragma unroll
            for (int r = 0; r < 4; ++r) sum[r] = 0.f;
            #pragma unroll
            for (int nt = 0; nt < 4; ++nt)
                #pragma unroll
                for (int r = 0; r < 4; ++r) {
                    const float e = (nt == 3 && !v3) ? 0.f
                                  : __expf((s[m][nt][r] - mx[r]) * 0.25f);  // SCALE=16^-0.5
                    s[m][nt][r] = e;
                    sum[r] += e;
                }
            #pragma unroll
            for (int d = 1; d <= 8; d <<= 1)
                #pragma unroll
                for (int r = 0; r < 4; ++r)
                    sum[r] += __shfl_xor(sum[r], d, 64);
            #pragma unroll
            for (int r = 0; r < 4; ++r) sum[r] = 1.0f / sum[r];
            #pragma unroll
            for (int nt = 0; nt < 4; ++nt)
                #pragma unroll
                for (int r = 0; r < 4; ++r) {
                    const int row = kg * 4 + r + 16 * m;
                    const int col = lr + 16 * nt;
                    r1[h * 4096 + row * 64 + (((col >> 3) ^ (row & 7)) << 3) + (col & 7)] =
                        f2bf(s[m][nt][r] * sum[r]);
                }
        }
    }
    __syncthreads();

    // ---- PV: O = P @ v_h  (K = 64 toks, N = 32 dims) ----
    f32x4 oacc[4][2];
    #pragma unroll
    for (int m = 0; m < 4; ++m) {
        oacc[m][0] = f32x4{0.f, 0.f, 0.f, 0.f};
        oacc[m][1] = f32x4{0.f, 0.f, 0.f, 0.f};
    }
    #pragma unroll
    for (int kt = 0; kt < 2; ++kt) {
        bf16x8 pa[4], vb[2];
        #pragma unroll
        for (int m = 0; m < 4; ++m) {
            const int row = lr + 16 * m;
            const int ch = (kt * 4 + kg) ^ (row & 7);
            pa[m] = *reinterpret_cast<const bf16x8*>(&r1[h * 4096 + row * 64 + ch * 8]);
        }
        #pragma unroll
        for (int nt = 0; nt < 2; ++nt) {
            const int d = lr + 16 * nt;                     // v dim = B col
            const int ch = (kt * 4 + kg) ^ (d & 7);
            vb[nt] = *reinterpret_cast<const bf16x8*>(&r3[h * 2048 + d * 64 + ch * 8]);
        }
        #pragma unroll
        for (int m = 0; m < 4; ++m)
            #pragma unroll
            for (int nt = 0; nt < 2; ++nt)
                oacc[m][nt] = __builtin_amdgcn_mfma_f32_16x16x32_bf16(pa[m], vb[nt], oacc[m][nt], 0, 0, 0);
    }
    __syncthreads();    // vT & p_s dead

    // write o_s[64][128] into r3 (overlay vT)
    #pragma unroll
    for (int m = 0; m < 4; ++m)
        #pragma unroll
        for (int nt = 0; nt < 2; ++nt)
            #pragma unroll
            for (int r = 0; r < 4; ++r) {
                const int row = kg * 4 + r + 16 * m;
                const int col = h * 32 + nt * 16 + lr;
                r3[row * 128 + (((col >> 3) ^ (row & 7)) << 3) + (col & 7)] = f2bf(oacc[m][nt][r]);
            }
    __syncthreads();

    // ---- proj: out = o_s @ Wproj + bproj ----
    f32x4 pc[4][4];
    #pragma unroll
    for (int m = 0; m < 4; ++m)
        #pragma unroll
        for (int nn = 0; nn < 4; ++nn)
            pc[m][nn] = f32x4{0.f, 0.f, 0.f, 0.f};

    #pragma unroll
    for (int kt = 0; kt < 4; ++kt) {
        bf16x8 a[4], bw[4];
        #pragma unroll
        for (int m = 0; m < 4; ++m) {
            const int row = lr + 16 * m;
            const int ch = (kt * 4 + kg) ^ (row & 7);
            a[m] = *reinterpret_cast<const bf16x8*>(&r3[row * 128 + ch * 8]);
        }
        #pragma unroll
        for (int nn = 0; nn < 4; ++nn) {
            const int nt = wave * 4 + nn;
            bw[nn] = *reinterpret_cast<const bf16x8*>(&wf[PROJ_OFF + ((nt * 4 + kt) * 64 + lane) * 8]);
        }
        #pragma unroll
        for (int m = 0; m < 4; ++m)
            #pragma unroll
            for (int nn = 0; nn < 4; ++nn)
                pc[m][nn] = __builtin_amdgcn_mfma_f32_16x16x32_bf16(a[m], bw[nn], pc[m][nn], 0, 0, 0);
    }

    // write out_s[64][256] into r1 (p_s dead since post-PV barrier)
    #pragma unroll
    for (int nn = 0; nn < 4; ++nn) {
        const int colg = wave * 64 + nn * 16 + lr;
        const float bp = bproj[colg];
        #pragma unroll
        for (int m = 0; m < 4; ++m)
            #pragma unroll
            for (int r = 0; r < 4; ++r) {
                const int row = kg * 4 + r + 16 * m;
                r1[row * 256 + (((colg >> 3) ^ (row & 7)) << 3) + (colg & 7)] = f2bf(pc[m][nn][r] + bp);
            }
    }
    __syncthreads();

    // ---- store: same 7-contiguous-float pattern as the loads ----
    if (lane < 49) {
        const int lb = xwin + (lane / 7) * 112 + (lane % 7);
        #pragma unroll 8
        for (int it = 0; it < 32; ++it) {
            const int c0 = wave * 64 + it * 2;
            const int e = lane * 256 + (((c0 >> 3) ^ (lane & 7)) << 3) + (c0 & 7);
            const unsigned int pk = *reinterpret_cast<const unsigned int*>(&r1[e]);
            out[lb + c0 * 12544] = bf2f(pk & 0xffffu);
            out[lb + (c0 + 1) * 12544] = bf2f(pk >> 16);
        }
    }
}

extern "C" void kernel_launch(void* const* d_in, const int* in_sizes, int n_in,
                              void* d_out, int out_size, void* d_ws, size_t ws_size,
                              hipStream_t stream) {
    const float* x     = (const float*)d_in[0];
    const float* Wqkv  = (const float*)d_in[1];
    const float* bqkv  = (const float*)d_in[2];
    const float* Wproj = (const float*)d_in[3];
    const float* bproj = (const float*)d_in[4];
    unsigned short* wf = (unsigned short*)d_ws;   // 192 KB used

    prep_weights<<<48, 256, 0, stream>>>(Wqkv, Wproj, wf);
    win_attn<<<8192, 256, 0, stream>>>(x, wf, bqkv, bproj, (float*)d_out);
}

// Round 2
// 440.805 us; speedup vs baseline: 1.1143x; 1.1143x over previous
//
#include <hip/hip_runtime.h>
#include <hip/hip_bf16.h>

// TinyLocalWindowAttention on MI355X (gfx950)
// x:(32,256,112,112) f32, 7x7 windows, 8192 windows; 1 block (4 waves) per window.
// bf16 MFMA 16x16x32 throughout. LDS 48KB -> 3 blocks/CU.

typedef short bf16x8 __attribute__((ext_vector_type(8)));   // 8 bf16 (4 VGPRs)
typedef float f32x4 __attribute__((ext_vector_type(4)));

static __device__ __forceinline__ unsigned short cvt1(float f) {
    __hip_bfloat16 h = __float2bfloat16(f);
    unsigned short u; __builtin_memcpy(&u, &h, 2); return u;
}
static __device__ __forceinline__ unsigned int cvt2(float a, float b) {
    float2 t; t.x = a; t.y = b;
    __hip_bfloat162 h = __float22bfloat162_rn(t);
    unsigned int u; __builtin_memcpy(&u, &h, 4); return u;
}
static __device__ __forceinline__ float bf2f(unsigned int hs) {
    return __uint_as_float(hs << 16);
}

#define PROJ_OFF 65536   // bf16 elems offset of proj frags in ws

// ---- pre-pass: Wqkv[256][256], Wproj[128][256] f32 -> bf16 B-fragment arrays ----
__global__ void prep_weights(const float* __restrict__ Wqkv,
                             const float* __restrict__ Wproj,
                             unsigned short* __restrict__ ws) {
    int tid = blockIdx.x * 256 + threadIdx.x;
    if (tid < 8192) {                         // 16 ntiles * 8 ktiles * 64 lanes
        int lane = tid & 63, f = tid >> 6;
        int kt = f & 7, nt = f >> 3;
        int kbase = kt * 32 + (lane >> 4) * 8;
        int col = nt * 16 + (lane & 15);
        uint4 u;
        u.x = cvt2(Wqkv[(kbase + 0) * 256 + col], Wqkv[(kbase + 1) * 256 + col]);
        u.y = cvt2(Wqkv[(kbase + 2) * 256 + col], Wqkv[(kbase + 3) * 256 + col]);
        u.z = cvt2(Wqkv[(kbase + 4) * 256 + col], Wqkv[(kbase + 5) * 256 + col]);
        u.w = cvt2(Wqkv[(kbase + 6) * 256 + col], Wqkv[(kbase + 7) * 256 + col]);
        *reinterpret_cast<uint4*>(&ws[tid * 8]) = u;
    } else if (tid < 12288) {                 // 16 ntiles * 4 ktiles * 64 lanes
        int i2 = tid - 8192;
        int lane = i2 & 63, f = i2 >> 6;
        int kt = f & 3, nt = f >> 2;
        int kbase = kt * 32 + (lane >> 4) * 8;
        int col = nt * 16 + (lane & 15);
        uint4 u;
        u.x = cvt2(Wproj[(kbase + 0) * 256 + col], Wproj[(kbase + 1) * 256 + col]);
        u.y = cvt2(Wproj[(kbase + 2) * 256 + col], Wproj[(kbase + 3) * 256 + col]);
        u.z = cvt2(Wproj[(kbase + 4) * 256 + col], Wproj[(kbase + 5) * 256 + col]);
        u.w = cvt2(Wproj[(kbase + 6) * 256 + col], Wproj[(kbase + 7) * 256 + col]);
        *reinterpret_cast<uint4*>(&ws[PROJ_OFF + i2 * 8]) = u;
    }
}

// LDS (48 KB total -> 3 blocks/CU):
//  A [32KB]: xa[64][256] -> { p[4 heads][32][64] @0 ; vT[4][32 d][64 tok] @8192 } -> out_s[64][256]
//  B [16KB]: qk[64][128] (q cols 0..63, k cols 64..127) -> o_s[64][128]
// swizzle: elem(row,col,W) = row*W + (((col>>3) ^ (row&7))<<3) + (col&7)

__global__ __launch_bounds__(256, 3) void win_attn(
    const float* __restrict__ x,
    const unsigned short* __restrict__ wf,
    const float* __restrict__ bqkv,
    const float* __restrict__ bproj,
    float* __restrict__ out)
{
    __shared__ __align__(16) unsigned short A[16384];
    __shared__ __align__(16) unsigned short B[8192];

    const int tid  = threadIdx.x;
    const int lane = tid & 63;
    const int wave = tid >> 6;
    const int lr   = lane & 15;       // row/col within 16-tile
    const int kg   = lane >> 4;       // k-group (0..3)

    // XCD swizzle: contiguous 1024 windows per XCD
    const int bid = (int)blockIdx.x;
    const int L   = (bid & 7) * 1024 + (bid >> 3);
    const int b   = L >> 8;
    const int rem = L & 255;
    const int h0 = (rem >> 4) * 7;
    const int w0 = (rem & 15) * 7;
    const int xwin = (b * 256) * 12544 + h0 * 112 + w0;

    // preload biases (early, hides latency)
    float bqv[4], bpv[4];
    #pragma unroll
    for (int nn = 0; nn < 4; ++nn) {
        bqv[nn] = bqkv[wave * 64 + nn * 16 + lr];
        bpv[nn] = bproj[wave * 64 + nn * 16 + lr];
    }

    // ---- phase A: zero pad rows 49..63, load x window -> xa (bf16) ----
    for (int i = tid; i < 15 * 128; i += 256)
        reinterpret_cast<unsigned int*>(A)[49 * 128 + i] = 0u;

    if (lane < 49) {
        const int lb = xwin + (lane / 7) * 112 + (lane % 7);
        #pragma unroll 8
        for (int it = 0; it < 32; ++it) {
            const int c0 = wave * 64 + it * 2;
            const float v0 = x[lb + c0 * 12544];
            const float v1 = x[lb + (c0 + 1) * 12544];
            const int e = lane * 256 + (((c0 >> 3) ^ (lane & 7)) << 3) + (c0 & 7);
            *reinterpret_cast<unsigned int*>(&A[e]) = cvt2(v0, v1);
        }
    }
    __syncthreads();

    // ---- phase B: qkv = xa @ Wqkv ; wave w owns output cols [64w, 64w+64) ----
    f32x4 acc[4][4];
    #pragma unroll
    for (int m = 0; m < 4; ++m)
        #pragma unroll
        for (int nn = 0; nn < 4; ++nn)
            acc[m][nn] = f32x4{0.f, 0.f, 0.f, 0.f};

    #pragma unroll
    for (int kt = 0; kt < 8; ++kt) {
        bf16x8 a[4], bw[4];
        #pragma unroll
        for (int m = 0; m < 4; ++m) {
            const int row = lr + 16 * m;
            const int ch  = (kt * 4 + kg) ^ (row & 7);
            a[m] = *reinterpret_cast<const bf16x8*>(&A[row * 256 + ch * 8]);
        }
        #pragma unroll
        for (int nn = 0; nn < 4; ++nn) {
            const int nt = wave * 4 + nn;
            bw[nn] = *reinterpret_cast<const bf16x8*>(&wf[((nt * 8 + kt) * 64 + lane) * 8]);
        }
        #pragma unroll
        for (int m = 0; m < 4; ++m)
            #pragma unroll
            for (int nn = 0; nn < 4; ++nn)
                acc[m][nn] = __builtin_amdgcn_mfma_f32_16x16x32_bf16(a[m], bw[nn], acc[m][nn], 0, 0, 0);
    }
    __syncthreads();   // all waves done READING xa (vT will overlay it)

    // epilogue: +bias; waves 0,1 -> q/k in B; waves 2,3 -> vT in A[8192..)
    #pragma unroll
    for (int nn = 0; nn < 4; ++nn) {
        const int colg = wave * 64 + nn * 16 + lr;
        #pragma unroll
        for (int m = 0; m < 4; ++m)
            #pragma unroll
            for (int r = 0; r < 4; ++r) {
                const int row = kg * 4 + r + 16 * m;        // token
                const unsigned short hv = cvt1(acc[m][nn][r] + bqv[nn]);
                if (wave < 2) {
                    B[row * 128 + (((colg >> 3) ^ (row & 7)) << 3) + (colg & 7)] = hv;
                } else {
                    const int vc = colg - 128;
                    const int hh = vc >> 5, d = vc & 31;
                    A[8192 + hh * 2048 + d * 64 + (((row >> 3) ^ (d & 7)) << 3) + (row & 7)] = hv;
                }
            }
    }
    __syncthreads();

    // ---- attention, head h = wave; S = q_h @ k_h^T (K=16 padded to 32) ----
    const int h = wave;
    f32x4 s[4][4];
    {
        bf16x8 qf[4], kf[4];
        const bf16x8 zf = {0, 0, 0, 0, 0, 0, 0, 0};
        #pragma unroll
        for (int m = 0; m < 4; ++m) {
            if (lane < 32) {
                const int row = lr + 16 * m;
                const int col = h * 16 + kg * 8;
                qf[m] = *reinterpret_cast<const bf16x8*>(&B[row * 128 + (((col >> 3) ^ (row & 7)) << 3)]);
            } else qf[m] = zf;
        }
        #pragma unroll
        for (int nt = 0; nt < 4; ++nt) {
            if (lane < 32) {
                const int row = lr + 16 * nt;               // k-token
                const int col = 64 + h * 16 + kg * 8;
                kf[nt] = *reinterpret_cast<const bf16x8*>(&B[row * 128 + (((col >> 3) ^ (row & 7)) << 3)]);
            } else kf[nt] = zf;
        }
        #pragma unroll
        for (int m = 0; m < 4; ++m)
            #pragma unroll
            for (int nt = 0; nt < 4; ++nt) {
                f32x4 z = f32x4{0.f, 0.f, 0.f, 0.f};
                s[m][nt] = __builtin_amdgcn_mfma_f32_16x16x32_bf16(qf[m], kf[nt], z, 0, 0, 0);
            }
    }

    // hoist V fragments (B-operand of PV)
    bf16x8 vb[2][2];
    #pragma unroll
    for (int kt = 0; kt < 2; ++kt)
        #pragma unroll
        for (int nt = 0; nt < 2; ++nt) {
            const int d = lr + 16 * nt;
            const int ch = (kt * 4 + kg) ^ (d & 7);
            vb[kt][nt] = *reinterpret_cast<const bf16x8*>(&A[8192 + h * 2048 + d * 64 + ch * 8]);
        }

    // softmax (deferred normalization) + PV, two m-halves through a 32-row P buffer
    f32x4 oacc[4][2];
    #pragma unroll
    for (int m = 0; m < 4; ++m) {
        oacc[m][0] = f32x4{0.f, 0.f, 0.f, 0.f};
        oacc[m][1] = f32x4{0.f, 0.f, 0.f, 0.f};
    }
    float rs[4][4];
    const bool v3 = (lr == 0);  // in nt==3 only col 48 is valid

    #pragma unroll
    for (int mh = 0; mh < 2; ++mh) {
        #pragma unroll
        for (int m2 = 0; m2 < 2; ++m2) {
            const int m = mh * 2 + m2;
            float mx[4], sum[4];
            #pragma unroll
            for (int r = 0; r < 4; ++r) {
                const float a0 = fmaxf(s[m][0][r], s[m][1][r]);
                const float a1 = v3 ? fmaxf(s[m][2][r], s[m][3][r]) : s[m][2][r];
                mx[r] = fmaxf(a0, a1);
            }
            #pragma unroll
            for (int d = 1; d <= 8; d <<= 1)
                #pragma unroll
                for (int r = 0; r < 4; ++r)
                    mx[r] = fmaxf(mx[r], __shfl_xor(mx[r], d, 64));
            #pragma unroll
            for (int r = 0; r < 4; ++r) sum[r] = 0.f;
            #pragma unroll
            for (int nt = 0; nt < 4; ++nt)
                #pragma unroll
                for (int r = 0; r < 4; ++r) {
                    const float e = (nt == 3 && !v3) ? 0.f
                                  : __expf((s[m][nt][r] - mx[r]) * 0.25f);  // SCALE=16^-0.5
                    s[m][nt][r] = e;
                    sum[r] += e;
                }
            #pragma unroll
            for (int d = 1; d <= 8; d <<= 1)
                #pragma unroll
                for (int r = 0; r < 4; ++r)
                    sum[r] += __shfl_xor(sum[r], d, 64);
            #pragma unroll
            for (int r = 0; r < 4; ++r) rs[m][r] = __builtin_amdgcn_rcpf(sum[r]);
            // write unnormalized P rows (kg*4+r+16*m2) of this half
            #pragma unroll
            for (int nt = 0; nt < 4; ++nt)
                #pragma unroll
                for (int r = 0; r < 4; ++r) {
                    const int rw = kg * 4 + r + 16 * m2;
                    const int col = lr + 16 * nt;
                    A[h * 2048 + rw * 64 + (((col >> 3) ^ (rw & 7)) << 3) + (col & 7)] =
                        cvt1(s[m][nt][r]);
                }
        }
        // PV for this half (wave-private buffer: no barrier, compiler handles lgkmcnt)
        #pragma unroll
        for (int kt = 0; kt < 2; ++kt) {
            bf16x8 pa[2];
            #pragma unroll
            for (int m2 = 0; m2 < 2; ++m2) {
                const int rw = lr + 16 * m2;
                const int ch = (kt * 4 + kg) ^ (rw & 7);
                pa[m2] = *reinterpret_cast<const bf16x8*>(&A[h * 2048 + rw * 64 + ch * 8]);
            }
            #pragma unroll
            for (int m2 = 0; m2 < 2; ++m2)
                #pragma unroll
                for (int nt = 0; nt < 2; ++nt)
                    oacc[mh * 2 + m2][nt] =
                        __builtin_amdgcn_mfma_f32_16x16x32_bf16(pa[m2], vb[kt][nt], oacc[mh * 2 + m2][nt], 0, 0, 0);
        }
    }
    // apply deferred 1/sum
    #pragma unroll
    for (int m = 0; m < 4; ++m)
        #pragma unroll
        for (int nt = 0; nt < 2; ++nt)
            #pragma unroll
            for (int r = 0; r < 4; ++r)
                oacc[m][nt][r] *= rs[m][r];

    __syncthreads();   // p/vT dead; q/k dead -> o_s overlays B

    #pragma unroll
    for (int m = 0; m < 4; ++m)
        #pragma unroll
        for (int nt = 0; nt < 2; ++nt)
            #pragma unroll
            for (int r = 0; r < 4; ++r) {
                const int row = kg * 4 + r + 16 * m;
                const int col = h * 32 + nt * 16 + lr;
                B[row * 128 + (((col >> 3) ^ (row & 7)) << 3) + (col & 7)] = cvt1(oacc[m][nt][r]);
            }
    __syncthreads();

    // ---- proj: out = o_s @ Wproj + bproj ----
    f32x4 pc[4][4];
    #pragma unroll
    for (int m = 0; m < 4; ++m)
        #pragma unroll
        for (int nn = 0; nn < 4; ++nn)
            pc[m][nn] = f32x4{0.f, 0.f, 0.f, 0.f};

    #pragma unroll
    for (int kt = 0; kt < 4; ++kt) {
        bf16x8 a[4], bw[4];
        #pragma unroll
        for (int m = 0; m < 4; ++m) {
            const int row = lr + 16 * m;
            const int ch = (kt * 4 + kg) ^ (row & 7);
            a[m] = *reinterpret_cast<const bf16x8*>(&B[row * 128 + ch * 8]);
        }
        #pragma unroll
        for (int nn = 0; nn < 4; ++nn) {
            const int nt = wave * 4 + nn;
            bw[nn] = *reinterpret_cast<const bf16x8*>(&wf[PROJ_OFF + ((nt * 4 + kt) * 64 + lane) * 8]);
        }
        #pragma unroll
        for (int m = 0; m < 4; ++m)
            #pragma unroll
            for (int nn = 0; nn < 4; ++nn)
                pc[m][nn] = __builtin_amdgcn_mfma_f32_16x16x32_bf16(a[m], bw[nn], pc[m][nn], 0, 0, 0);
    }

    // write out_s[64][256] into A (p/vT dead since post-PV barrier)
    #pragma unroll
    for (int nn = 0; nn < 4; ++nn) {
        const int colg = wave * 64 + nn * 16 + lr;
        #pragma unroll
        for (int m = 0; m < 4; ++m)
            #pragma unroll
            for (int r = 0; r < 4; ++r) {
                const int row = kg * 4 + r + 16 * m;
                A[row * 256 + (((colg >> 3) ^ (row & 7)) << 3) + (colg & 7)] = cvt1(pc[m][nn][r] + bpv[nn]);
            }
    }
    __syncthreads();

    // ---- store: same 7-contiguous-float pattern as the loads ----
    if (lane < 49) {
        const int lb = xwin + (lane / 7) * 112 + (lane % 7);
        #pragma unroll 8
        for (int it = 0; it < 32; ++it) {
            const int c0 = wave * 64 + it * 2;
            const int e = lane * 256 + (((c0 >> 3) ^ (lane & 7)) << 3) + (c0 & 7);
            const unsigned int pk = *reinterpret_cast<const unsigned int*>(&A[e]);
            out[lb + c0 * 12544] = bf2f(pk & 0xffffu);
            out[lb + (c0 + 1) * 12544] = bf2f(pk >> 16);
        }
    }
}

extern "C" void kernel_launch(void* const* d_in, const int* in_sizes, int n_in,
                              void* d_out, int out_size, void* d_ws, size_t ws_size,
                              hipStream_t stream) {
    const float* x     = (const float*)d_in[0];
    const float* Wqkv  = (const float*)d_in[1];
    const float* bqkv  = (const float*)d_in[2];
    const float* Wproj = (const float*)d_in[3];
    const float* bproj = (const float*)d_in[4];
    unsigned short* wf = (unsigned short*)d_ws;   // 192 KB used

    prep_weights<<<48, 256, 0, stream>>>(Wqkv, Wproj, wf);
    win_attn<<<8192, 256, 0, stream>>>(x, wf, bqkv, bproj, (float*)d_out);
}